// Round 4
// baseline (285.752 us; speedup 1.0000x reference)
//
#include <hip/hip_runtime.h>

typedef __attribute__((ext_vector_type(8))) short short8;
typedef __attribute__((ext_vector_type(4))) float floatx4;

#define CCH   256
#define QSCALE 0.17677669529663687f  // 32^-0.5

__device__ __forceinline__ unsigned short f2bf(float f) {
    unsigned u = __float_as_uint(f);
    u = u + 0x7fffu + ((u >> 16) & 1u);
    return (unsigned short)(u >> 16);
}
__device__ __forceinline__ float bf2f(unsigned short h) {
    return __uint_as_float(((unsigned)h) << 16);
}

__device__ __forceinline__ void gl_lds16(const void* g, void* l) {
    __builtin_amdgcn_global_load_lds((const __attribute__((address_space(1))) void*)g,
                                     (__attribute__((address_space(3))) void*)l, 16, 0, 0);
}

// token (w*512+n) -> flat spatial offset (*CCH) in x/out with +4 cyclic shift
__device__ __forceinline__ int spatial_off(int token) {
    int w = token >> 9, n = token & 511;
    int wh = w >> 4, ww = (w >> 2) & 3, wd = w & 3;
    int h1 = n >> 6, w1 = (n >> 3) & 7, d1 = n & 7;
    int gh = (wh * 8 + h1 + 4) & 31;
    int gw = (ww * 8 + w1 + 4) & 31;
    int gd = (wd * 8 + d1 + 4) & 31;
    return ((gh * 32 + gw) * 32 + gd) * CCH;
}

// ---------------- x (fp32, spatial) -> Xw (bf16, window-token order) ----------------
__global__ __launch_bounds__(256) void xconv(const float* __restrict__ x,
                                             ushort* __restrict__ Xw) {
    int tid = blockIdx.x * 256 + threadIdx.x;   // 1048576
    int token = tid >> 5, c8 = (tid & 31) * 8;
    const float* src = x + spatial_off(token) + c8;
    float4 a = *(const float4*)src;
    float4 b = *(const float4*)(src + 4);
    ushort o[8] = {f2bf(a.x), f2bf(a.y), f2bf(a.z), f2bf(a.w),
                   f2bf(b.x), f2bf(b.y), f2bf(b.z), f2bf(b.w)};
    *(short8*)(Xw + (size_t)token * 256 + c8) = *(short8*)o;
}

// ---------------- weights fp32 -> bf16 (QSCALE folded into first 256 rows of Wq) ----
__global__ __launch_bounds__(256) void wconv(const float* __restrict__ Wq,
                                             const float* __restrict__ Wp,
                                             ushort* __restrict__ Wqb,
                                             ushort* __restrict__ Wpb) {
    int tid = blockIdx.x * 256 + threadIdx.x;   // 262144
    if (tid < 196608) {
        float s = (tid < 65536) ? QSCALE : 1.0f;
        Wqb[tid] = f2bf(Wq[tid] * s);
    } else {
        int i = tid - 196608;
        Wpb[i] = f2bf(Wp[i]);
    }
}

// ---------------- rel-pos bias, pre-permuted into MFMA C-fragment order ----------------
__global__ __launch_bounds__(256) void bias_prep(const float* __restrict__ rpb,
                                                 ushort* __restrict__ BF) {
    int tid = blockIdx.x * 256 + threadIdx.x;   // 524288 total
    int lane = tid & 63, kt = (tid >> 6) & 31, qt = (tid >> 11) & 31, head = tid >> 16;
    int quad = lane >> 4, colc = lane & 15;
    int key = kt * 16 + colc;
    int h1k = key >> 6, w1k = (key >> 3) & 7, d1k = key & 7;
    ushort4 out;
#pragma unroll
    for (int r = 0; r < 4; ++r) {
        int qrow = qt * 16 + quad * 4 + r;
        int dh = (qrow >> 6) - h1k + 7;
        int dw = ((qrow >> 3) & 7) - w1k + 7;
        int dd = (qrow & 7) - d1k + 7;
        int idx = (dh * 15 + dw) * 15 + dd;
        ((ushort*)&out)[r] = f2bf(rpb[idx * 8 + head]);
    }
    *(ushort4*)(BF + (size_t)tid * 4) = out;
}

// ---------------- MFMA GEMM: C[32768 x 768] = Xw @ Wqb^T -> Q/K/Vf ----------------
// V stored pre-permuted into MFMA B-fragment order:
//   Vf[((w*8+head)*32 + (n>>5)*2 + (hd>>4))*512 + (((n>>3)&3)*16 + (hd&15))*8 + (n&7)]
__global__ __launch_bounds__(256) void gemm_qkv(
    const ushort* __restrict__ A,   // [32768][256] bf16
    const ushort* __restrict__ Bw,  // [768][256] bf16
    const float* __restrict__ bq,
    ushort* __restrict__ Q, ushort* __restrict__ K, ushort* __restrict__ Vf) {
    __shared__ short As[128 * 64];
    __shared__ short Bs[128 * 64];
    const int t = threadIdx.x;
    const int wv = t >> 6, lane = t & 63, quad = lane >> 4, col = lane & 15;
    const int m0 = blockIdx.y * 128, n0 = blockIdx.x * 128;
    const int wm = (wv & 1) * 64, wn = (wv >> 1) * 64;

    floatx4 zf = {0.f, 0.f, 0.f, 0.f};
    floatx4 acc[4][4];
#pragma unroll
    for (int i = 0; i < 4; ++i)
#pragma unroll
        for (int j = 0; j < 4; ++j) acc[i][j] = zf;

    for (int kk = 0; kk < 256; kk += 64) {
        __syncthreads();
#pragma unroll
        for (int i = 0; i < 4; ++i) {
            int s = i * 256 + t;
            int row = s >> 3, qs = s & 7;
            int qg = qs ^ (row & 7);
            gl_lds16(A + (size_t)(m0 + row) * 256 + kk + qg * 8,
                     As + (i * 256 + wv * 64) * 8);
        }
#pragma unroll
        for (int i = 0; i < 4; ++i) {
            int s = i * 256 + t;
            int row = s >> 3, qs = s & 7;
            int qg = qs ^ (row & 7);
            gl_lds16(Bw + (size_t)(n0 + row) * 256 + kk + qg * 8,
                     Bs + (i * 256 + wv * 64) * 8);
        }
        __syncthreads();
#pragma unroll
        for (int h = 0; h < 2; ++h) {
            short8 af[4], bf[4];
#pragma unroll
            for (int mi = 0; mi < 4; ++mi) {
                int row = wm + mi * 16 + col;
                af[mi] = *(const short8*)(As + (row * 8 + ((h * 4 + quad) ^ (row & 7))) * 8);
            }
#pragma unroll
            for (int ni = 0; ni < 4; ++ni) {
                int row = wn + ni * 16 + col;
                bf[ni] = *(const short8*)(Bs + (row * 8 + ((h * 4 + quad) ^ (row & 7))) * 8);
            }
#pragma unroll
            for (int mi = 0; mi < 4; ++mi)
#pragma unroll
                for (int ni = 0; ni < 4; ++ni)
                    acc[mi][ni] = __builtin_amdgcn_mfma_f32_16x16x32_bf16(af[mi], bf[ni], acc[mi][ni], 0, 0, 0);
        }
    }

#pragma unroll
    for (int ni = 0; ni < 4; ++ni) {
        int j = n0 + wn + ni * 16 + col;
        int three = j >> 8, head = (j >> 5) & 7, hd = j & 31;
        float bias = bq[j] * ((j < 256) ? QSCALE : 1.0f);
        if (three == 2) {
#pragma unroll
            for (int mi = 0; mi < 4; ++mi) {
#pragma unroll
                for (int r = 0; r < 4; ++r) {
                    int m = m0 + wm + mi * 16 + quad * 4 + r;
                    int w = m >> 9, n = m & 511;
                    size_t off = ((size_t)((w * 8 + head) * 32 + ((n >> 5) << 1) + (hd >> 4)) << 9)
                               + ((((n >> 3) & 3) << 4) + (hd & 15)) * 8 + (n & 7);
                    Vf[off] = f2bf(acc[mi][ni][r] + bias);
                }
            }
        } else {
            ushort* dst = (three == 0) ? Q : K;
#pragma unroll
            for (int mi = 0; mi < 4; ++mi) {
#pragma unroll
                for (int r = 0; r < 4; ++r) {
                    int m = m0 + wm + mi * 16 + quad * 4 + r;
                    int w = m >> 9, n = m & 511;
                    dst[((size_t)(w * 8 + head) * 512 + n) * 32 + hd] = f2bf(acc[mi][ni][r] + bias);
                }
            }
        }
    }
}

// ---------------- MFMA GEMM: out = Y @ Wpb^T + bp, scatter w/ reverse shift ----------
__global__ __launch_bounds__(256) void gemm_proj(
    const ushort* __restrict__ A,   // Y [32768][256] bf16
    const ushort* __restrict__ Bw,  // [256][256] bf16
    const float* __restrict__ bp,
    float* __restrict__ out) {
    __shared__ short As[128 * 64];
    __shared__ short Bs[128 * 64];
    const int t = threadIdx.x;
    const int wv = t >> 6, lane = t & 63, quad = lane >> 4, col = lane & 15;
    const int m0 = blockIdx.y * 128, n0 = blockIdx.x * 128;
    const int wm = (wv & 1) * 64, wn = (wv >> 1) * 64;

    floatx4 zf = {0.f, 0.f, 0.f, 0.f};
    floatx4 acc[4][4];
#pragma unroll
    for (int i = 0; i < 4; ++i)
#pragma unroll
        for (int j = 0; j < 4; ++j) acc[i][j] = zf;

    for (int kk = 0; kk < 256; kk += 64) {
        __syncthreads();
#pragma unroll
        for (int i = 0; i < 4; ++i) {
            int s = i * 256 + t;
            int row = s >> 3, qs = s & 7;
            int qg = qs ^ (row & 7);
            gl_lds16(A + (size_t)(m0 + row) * 256 + kk + qg * 8,
                     As + (i * 256 + wv * 64) * 8);
        }
#pragma unroll
        for (int i = 0; i < 4; ++i) {
            int s = i * 256 + t;
            int row = s >> 3, qs = s & 7;
            int qg = qs ^ (row & 7);
            gl_lds16(Bw + (size_t)(n0 + row) * 256 + kk + qg * 8,
                     Bs + (i * 256 + wv * 64) * 8);
        }
        __syncthreads();
#pragma unroll
        for (int h = 0; h < 2; ++h) {
            short8 af[4], bf[4];
#pragma unroll
            for (int mi = 0; mi < 4; ++mi) {
                int row = wm + mi * 16 + col;
                af[mi] = *(const short8*)(As + (row * 8 + ((h * 4 + quad) ^ (row & 7))) * 8);
            }
#pragma unroll
            for (int ni = 0; ni < 4; ++ni) {
                int row = wn + ni * 16 + col;
                bf[ni] = *(const short8*)(Bs + (row * 8 + ((h * 4 + quad) ^ (row & 7))) * 8);
            }
#pragma unroll
            for (int mi = 0; mi < 4; ++mi)
#pragma unroll
                for (int ni = 0; ni < 4; ++ni)
                    acc[mi][ni] = __builtin_amdgcn_mfma_f32_16x16x32_bf16(af[mi], bf[ni], acc[mi][ni], 0, 0, 0);
        }
    }

#pragma unroll
    for (int ni = 0; ni < 4; ++ni) {
        int j = n0 + wn + ni * 16 + col;
        float bias = bp[j];
#pragma unroll
        for (int mi = 0; mi < 4; ++mi) {
#pragma unroll
            for (int r = 0; r < 4; ++r) {
                int m = m0 + wm + mi * 16 + quad * 4 + r;
                out[spatial_off(m) + j] = acc[mi][ni][r] + bias;
            }
        }
    }
}

// ---------------- MFMA windowed attention: block = (window, head), qs-loop inside ----
__global__ __launch_bounds__(256, 2) void attn_kernel(
    const ushort* __restrict__ Q, const ushort* __restrict__ K,
    const ushort* __restrict__ Vf, const ushort* __restrict__ BF,
    ushort* __restrict__ Y) {
    __shared__ short Kl[512 * 32];       // row-major [key][hd] bf16
    __shared__ short Vs[512 * 32];       // B-fragment order (pre-permuted in global)
    __shared__ short Ps[4][16 * 40];     // per-wave P transpose buffer (stride 40)

    const int t = threadIdx.x;
    const int bid = blockIdx.x;
    const int w = bid >> 3, head = bid & 7;
    const int wh = w >> 4, ww = (w >> 2) & 3, wd = w & 3;
    const int wv = t >> 6, lane = t & 63, quad = lane >> 4, col = lane & 15;

    const ushort* Kg = K + (size_t)(w * 8 + head) * 512 * 32;
    const ushort* Vg = Vf + (size_t)(w * 8 + head) * 512 * 32;
    const ushort* Qg = Q + (size_t)(w * 8 + head) * 512 * 32;

    // ---- stage K and V once (async direct-to-LDS, linear) ----
#pragma unroll
    for (int i = 0; i < 8; ++i) {
        gl_lds16(Kg + (size_t)(i * 256 + t) * 8, Kl + (i * 256 + wv * 64) * 8);
        gl_lds16(Vg + (size_t)(i * 256 + t) * 8, Vs + (i * 256 + wv * 64) * 8);
    }

    // preload all 8 Q fragments for this wave (overlaps staging latency)
    short8 qfs[8];
#pragma unroll
    for (int qs = 0; qs < 8; ++qs) {
        int qt = wv * 8 + qs;
        qfs[qs] = *(const short8*)(Qg + (size_t)(qt * 16 + col) * 32 + quad * 8);
    }
    __syncthreads();

    const bool boundary = (wh == 3) | (ww == 3) | (wd == 3);
    floatx4 zf = {0.f, 0.f, 0.f, 0.f};
    short* PsW = &Ps[wv][0];

    for (int qs = 0; qs < 8; ++qs) {
        const int qt = wv * 8 + qs;
        const short8 qf = qfs[qs];

        floatx4 acc[32];
#pragma unroll
        for (int tt = 0; tt < 32; ++tt) {
            short8 kf = *(const short8*)(Kl + tt * 512 + col * 32 + quad * 8);
            acc[tt] = __builtin_amdgcn_mfma_f32_16x16x32_bf16(qf, kf, zf, 0, 0, 0);
        }

        // ---- bias + shift mask ----
        const ushort* bfp = BF + ((size_t)(head * 32 + qt) * 32 * 64 + lane) * 4;
        int cq[4];
#pragma unroll
        for (int r = 0; r < 4; ++r) {
            int qrow = qt * 16 + quad * 4 + r;
            int ch = (wh == 3) ? (1 + ((qrow >> 8) & 1)) : 0;
            int cw = (ww == 3) ? (1 + ((qrow >> 5) & 1)) : 0;
            int cd = (wd == 3) ? (1 + ((qrow >> 2) & 1)) : 0;
            cq[r] = ch * 16 + cw * 4 + cd;
        }
#pragma unroll
        for (int tt = 0; tt < 32; ++tt) {
            ushort4 bv = *(const ushort4*)(bfp + tt * 256);
            acc[tt][0] += bf2f(bv.x);
            acc[tt][1] += bf2f(bv.y);
            acc[tt][2] += bf2f(bv.z);
            acc[tt][3] += bf2f(bv.w);
            if (boundary) {
                int key = tt * 16 + col;
                int ch = (wh == 3) ? (1 + ((key >> 8) & 1)) : 0;
                int cw = (ww == 3) ? (1 + ((key >> 5) & 1)) : 0;
                int cd = (wd == 3) ? (1 + ((key >> 2) & 1)) : 0;
                int ck = ch * 16 + cw * 4 + cd;
#pragma unroll
                for (int r = 0; r < 4; ++r)
                    acc[tt][r] += (cq[r] == ck) ? 0.f : -100.f;
            }
        }

        // ---- register-resident softmax ----
        float rm[4], rs[4];
#pragma unroll
        for (int r = 0; r < 4; ++r) {
            float m = acc[0][r];
#pragma unroll
            for (int tt = 1; tt < 32; ++tt) m = fmaxf(m, acc[tt][r]);
            m = fmaxf(m, __shfl_xor(m, 1));
            m = fmaxf(m, __shfl_xor(m, 2));
            m = fmaxf(m, __shfl_xor(m, 4));
            m = fmaxf(m, __shfl_xor(m, 8));
            rm[r] = m * 1.442695041f;
            rs[r] = 0.f;
        }
#pragma unroll
        for (int tt = 0; tt < 32; ++tt) {
#pragma unroll
            for (int r = 0; r < 4; ++r) {
                float e = exp2f(fmaf(acc[tt][r], 1.442695041f, -rm[r]));
                acc[tt][r] = e;
                rs[r] += e;
            }
        }
#pragma unroll
        for (int r = 0; r < 4; ++r) {
            rs[r] += __shfl_xor(rs[r], 1);
            rs[r] += __shfl_xor(rs[r], 2);
            rs[r] += __shfl_xor(rs[r], 4);
            rs[r] += __shfl_xor(rs[r], 8);
        }

        // ---- O = P V (C-layout -> A-layout via per-wave LDS round-trip) ----
        floatx4 o0 = zf, o1 = zf;
#pragma unroll
        for (int kt = 0; kt < 16; ++kt) {
#pragma unroll
            for (int ttt = 0; ttt < 2; ++ttt) {
                floatx4 p = acc[kt * 2 + ttt];
#pragma unroll
                for (int r = 0; r < 4; ++r)
                    PsW[(quad * 4 + r) * 40 + ttt * 16 + col] = (short)f2bf(p[r]);
            }
            asm volatile("s_waitcnt lgkmcnt(0)" ::: "memory");
            short8 pa = *(const short8*)(PsW + col * 40 + quad * 8);
            short8 v0 = *(const short8*)(Vs + (kt * 2 + 0) * 512 + lane * 8);
            short8 v1 = *(const short8*)(Vs + (kt * 2 + 1) * 512 + lane * 8);
            o0 = __builtin_amdgcn_mfma_f32_16x16x32_bf16(pa, v0, o0, 0, 0, 0);
            o1 = __builtin_amdgcn_mfma_f32_16x16x32_bf16(pa, v1, o1, 0, 0, 0);
            asm volatile("" ::: "memory");
        }

        // ---- epilogue: normalize, write Y tile (bf16) ----
        ushort* Yb = Y + ((size_t)(w * 512) + qt * 16) * 256 + head * 32;
#pragma unroll
        for (int r = 0; r < 4; ++r) {
            float inv = 1.0f / rs[r];
            int row = quad * 4 + r;
            Yb[row * 256 + col] = f2bf(o0[r] * inv);
            Yb[row * 256 + 16 + col] = f2bf(o1[r] * inv);
        }
    }
}

extern "C" void kernel_launch(void* const* d_in, const int* in_sizes, int n_in,
                              void* d_out, int out_size, void* d_ws, size_t ws_size,
                              hipStream_t stream) {
    const float* x      = (const float*)d_in[0];
    const float* qkv_w  = (const float*)d_in[1];
    const float* qkv_b  = (const float*)d_in[2];
    const float* proj_w = (const float*)d_in[3];
    const float* proj_b = (const float*)d_in[4];
    const float* rpb    = (const float*)d_in[5];
    float* out = (float*)d_out;

    // ws layout (ushorts): Xw 8.39M | Q 8.39M | K 8.39M | Vf 8.39M | Y 8.39M | BF 2.1M | Wqb | Wpb
    ushort* Xw  = (ushort*)d_ws;
    ushort* Q   = Xw + 8388608;
    ushort* K   = Q + 8388608;
    ushort* Vf  = K + 8388608;
    ushort* Y   = Vf + 8388608;
    ushort* BF  = Y + 8388608;
    ushort* Wqb = BF + 2097152;
    ushort* Wpb = Wqb + 196608;

    xconv<<<dim3(4096), dim3(256), 0, stream>>>(x, Xw);
    wconv<<<dim3(1024), dim3(256), 0, stream>>>(qkv_w, proj_w, Wqb, Wpb);
    bias_prep<<<dim3(2048), dim3(256), 0, stream>>>(rpb, BF);
    gemm_qkv<<<dim3(6, 256), dim3(256), 0, stream>>>(Xw, Wqb, qkv_b, Q, K, Vf);
    attn_kernel<<<dim3(512), dim3(256), 0, stream>>>(Q, K, Vf, BF, Y);
    gemm_proj<<<dim3(2, 256), dim3(256), 0, stream>>>(Y, Wpb, proj_b, out);
}